// Round 6
// baseline (259.300 us; speedup 1.0000x reference)
//
#include <hip/hip_runtime.h>

#define IMG 512
#define OUT_N 502
#define NPLANE 48
#define STRIPS 32            // 16 output rows per strip
#define SROWS 16
#define C1c 0.0001f
#define C2c 0.0004f
#define EV_OFF 264   // odd-column sub-block offset (float4 units) in row buffer

__device__ __forceinline__ float ssim_px(float mx, float my, float P, float M) {
    float A = mx*mx, B = my*my, mxy = mx*my;
    float sumsq = 0.5f*(P+M) - A - B;      // sigx2 + sigy2
    float sxy   = 0.25f*(P-M) - mxy;       // sigxy
    float num = (2.f*mxy + C1c) * (2.f*sxy + C2c);
    float den = (A + B + C1c) * (sumsq + C2c);
    return num / den;
}

// Block = full-width 512-col strip, 16 output rows, 256 threads (2 cols/thr).
// V-blur in 12-slot register ring (static idx), H-blur via LDS row buffer
// (parity-split layout). __launch_bounds__(256,5): VGPR cap 102 (granule 96)
// comfortably holds the ~84-reg ring state -> no spill, 5 blocks/CU = 20 w/CU.
__global__ __launch_bounds__(256, 5) void ssim_strip(
    const float* __restrict__ in, const float* __restrict__ tgt,
    const float* __restrict__ w, float* __restrict__ partial)
{
    __shared__ float4 buf[2][528];
    __shared__ float g1s[16];
    __shared__ float red[4];

    const int tid   = threadIdx.x;
    const int strip = blockIdx.x;
    const int plane = blockIdx.y;
    const int r0 = strip * SROWS;
    const float* __restrict__ ip = in  + (size_t)plane * (IMG*IMG);
    const float* __restrict__ tp = tgt + (size_t)plane * (IMG*IMG);

    // 1D factor = row sums of 2D kernel (exact: w2d = outer(g,g), sum g = 1)
    if (tid < 11) {
        float s = 0.f;
        #pragma unroll
        for (int j = 0; j < 11; ++j) s += w[tid*11 + j];
        g1s[tid] = s;
    }
    __syncthreads();
    float g[11];
    #pragma unroll
    for (int j = 0; j < 11; ++j)
        g[j] = __int_as_float(__builtin_amdgcn_readfirstlane(__float_as_int(g1s[j])));

    float4 rA[12], rB[12];     // V-ring: cols tid and tid+256
    float acc = 0.f;
    const int wrA = (tid >> 1) + (tid & 1) * EV_OFF;   // col tid
    const int wrB = wrA + 128;                          // col tid+256

#define SS_LOAD(KK) \
    float xa=0.f, ya=0.f, xb=0.f, yb=0.f; \
    { const int r_ = r0 + (KK); \
      if (r_ < IMG) { \
        const float* ipr = ip + r_ * IMG; \
        const float* tpr = tp + r_ * IMG; \
        xa = ipr[tid];       ya = tpr[tid]; \
        xb = ipr[tid + 256]; yb = tpr[tid + 256]; \
      } }

#define SS_HPH(KK, RP) \
    { const int oy_ = r0 + (KK) - 11; \
      if (oy_ < OUT_N) { \
        float A0=0.f,A1=0.f,A2=0.f,A3=0.f,B0=0.f,B1=0.f,B2=0.f,B3=0.f; \
        _Pragma("unroll") \
        for (int j = 0; j < 12; ++j) { \
          float4 v = buf[RP][tid + (j>>1) + (j&1)*EV_OFF]; \
          if (j <= 10) { float wj=g[j];   A0+=wj*v.x; A1+=wj*v.y; A2+=wj*v.z; A3+=wj*v.w; } \
          if (j >= 1)  { float wj=g[j-1]; B0+=wj*v.x; B1+=wj*v.y; B2+=wj*v.z; B3+=wj*v.w; } \
        } \
        const int c0_ = 2*tid; \
        if (c0_ < OUT_N)     acc += ssim_px(A0,A1,A2,A3); \
        if (c0_ + 1 < OUT_N) acc += ssim_px(B0,B1,B2,B3); \
      } }

#define SS_RING(SLOT) \
    { float sa_=xa+ya, da_=xa-ya; rA[SLOT] = make_float4(xa, ya, sa_*sa_, da_*da_); \
      float sb_=xb+yb, db_=xb-yb; rB[SLOT] = make_float4(xb, yb, sb_*sb_, db_*db_); }

#define SS_VWR(SLOT, WP) \
    { float4 va_ = make_float4(0.f,0.f,0.f,0.f); \
      float4 vb_ = make_float4(0.f,0.f,0.f,0.f); \
      _Pragma("unroll") \
      for (int i = 0; i < 11; ++i) { \
        const int sl_ = ((SLOT) + 2 + i) % 12;   /* input rows KK-10 .. KK */ \
        float wj = g[i]; \
        va_.x += wj*rA[sl_].x; va_.y += wj*rA[sl_].y; va_.z += wj*rA[sl_].z; va_.w += wj*rA[sl_].w; \
        vb_.x += wj*rB[sl_].x; vb_.y += wj*rB[sl_].y; vb_.z += wj*rB[sl_].z; vb_.w += wj*rB[sl_].w; \
      } \
      buf[WP][wrA] = va_; buf[WP][wrB] = vb_; }

#define SS_ITER(KK, SLOT, HEN, VEN) \
    { SS_LOAD(KK); \
      if (HEN) SS_HPH(KK, (((KK)&1)^1)); \
      SS_RING(SLOT); \
      if (VEN) SS_VWR(SLOT, ((KK)&1)); \
      if ((HEN) || (VEN)) __syncthreads(); }

    // k = 0..9: load + ring fill only (no LDS, no barrier)
    SS_ITER(0,0,0,0)  SS_ITER(1,1,0,0)  SS_ITER(2,2,0,0)  SS_ITER(3,3,0,0)
    SS_ITER(4,4,0,0)  SS_ITER(5,5,0,0)  SS_ITER(6,6,0,0)  SS_ITER(7,7,0,0)
    SS_ITER(8,8,0,0)  SS_ITER(9,9,0,0)
    // k = 10: first V write; k = 11..25: V + H (outputs r0 .. r0+14)
    SS_ITER(10,10,0,1)
    SS_ITER(11,11,1,1)
    SS_ITER(12,0,1,1)  SS_ITER(13,1,1,1)  SS_ITER(14,2,1,1)  SS_ITER(15,3,1,1)
    SS_ITER(16,4,1,1)  SS_ITER(17,5,1,1)  SS_ITER(18,6,1,1)  SS_ITER(19,7,1,1)
    SS_ITER(20,8,1,1)  SS_ITER(21,9,1,1)  SS_ITER(22,10,1,1) SS_ITER(23,11,1,1)
    SS_ITER(24,0,1,1)  SS_ITER(25,1,1,1)
    // tail: H for output row r0+15 (V row written at k=25 -> buf[1])
    SS_HPH(26, 1)

    // block reduction
    #pragma unroll
    for (int off = 32; off > 0; off >>= 1)
        acc += __shfl_down(acc, off, 64);
    const int lane = tid & 63, wv = tid >> 6;
    if (lane == 0) red[wv] = acc;
    __syncthreads();
    if (tid == 0)
        partial[plane * STRIPS + strip] = red[0] + red[1] + red[2] + red[3];
}

// Deterministic final reduction: fixed traversal, double accumulation.
__global__ __launch_bounds__(256) void ssim_final(
    const float* __restrict__ partial, int n, float* __restrict__ out)
{
    __shared__ double red[256];
    double s = 0.0;
    for (int i = threadIdx.x; i < n; i += 256) s += (double)partial[i];
    red[threadIdx.x] = s;
    __syncthreads();
    for (int off = 128; off > 0; off >>= 1) {
        if (threadIdx.x < off) red[threadIdx.x] += red[threadIdx.x + off];
        __syncthreads();
    }
    if (threadIdx.x == 0) out[0] = (float)(1.0 - red[0] / (double)NPLANE);
}

extern "C" void kernel_launch(void* const* d_in, const int* in_sizes, int n_in,
                              void* d_out, int out_size, void* d_ws, size_t ws_size,
                              hipStream_t stream) {
    const float* in  = (const float*)d_in[0];
    const float* tgt = (const float*)d_in[1];
    const float* wt  = (const float*)d_in[2];
    float* out  = (float*)d_out;
    float* part = (float*)d_ws;

    dim3 grid(STRIPS, NPLANE);   // 32 row-strips x 48 planes = 1536 blocks
    ssim_strip<<<grid, 256, 0, stream>>>(in, tgt, wt, part);
    ssim_final<<<1, 256, 0, stream>>>(part, STRIPS * NPLANE, out);
}

// Round 7
// 56.308 us; speedup vs baseline: 4.6051x; 4.6051x over previous
//
#include <hip/hip_runtime.h>

#define IMG 512
#define OUT_N 502
#define NPLANE 48
#define STRIPS 32            // 16 output rows per strip
#define SROWS 16
#define C1c 0.0001f
#define C2c 0.0004f
#define EV_OFF 264   // odd-column sub-block offset (float4 units) in row buffer

__device__ __forceinline__ float ssim_px(float mx, float my, float P, float M) {
    float A = mx*mx, B = my*my, mxy = mx*my;
    float sumsq = 0.5f*(P+M) - A - B;      // sigx2 + sigy2
    float sxy   = 0.25f*(P-M) - mxy;       // sigxy
    float num = (2.f*mxy + C1c) * (2.f*sxy + C2c);
    float den = (A + B + C1c) * (sumsq + C2c);
    return num / den;
}

// Block = full-width 512-col strip, 16 output rows, 256 threads (2 cols/thr).
// V-blur in 12-slot register ring (static idx), H-blur via LDS row buffer
// (parity-split layout). __launch_bounds__(256,3): hipcc's cap rule is
// ~floor(256/w) -> w=3 gives 84 regs, the exact no-spill allocation proven in
// R3 (w>=4 caps below the ring's ~84-reg need and spills catastrophically).
// HW residency at 84 VGPR is 5 blocks/CU; grid 1536 = 6/CU of work feeds it.
__global__ __launch_bounds__(256, 3) void ssim_strip(
    const float* __restrict__ in, const float* __restrict__ tgt,
    const float* __restrict__ w, float* __restrict__ partial)
{
    __shared__ float4 buf[2][528];
    __shared__ float g1s[16];
    __shared__ float red[4];

    const int tid   = threadIdx.x;
    const int strip = blockIdx.x;
    const int plane = blockIdx.y;
    const int r0 = strip * SROWS;
    const float* __restrict__ ip = in  + (size_t)plane * (IMG*IMG);
    const float* __restrict__ tp = tgt + (size_t)plane * (IMG*IMG);

    // 1D factor = row sums of 2D kernel (exact: w2d = outer(g,g), sum g = 1)
    if (tid < 11) {
        float s = 0.f;
        #pragma unroll
        for (int j = 0; j < 11; ++j) s += w[tid*11 + j];
        g1s[tid] = s;
    }
    __syncthreads();
    float g[11];
    #pragma unroll
    for (int j = 0; j < 11; ++j)
        g[j] = __int_as_float(__builtin_amdgcn_readfirstlane(__float_as_int(g1s[j])));

    float4 rA[12], rB[12];     // V-ring: cols tid and tid+256
    float acc = 0.f;
    const int wrA = (tid >> 1) + (tid & 1) * EV_OFF;   // col tid
    const int wrB = wrA + 128;                          // col tid+256

#define SS_LOAD(KK) \
    float xa=0.f, ya=0.f, xb=0.f, yb=0.f; \
    { const int r_ = r0 + (KK); \
      if (r_ < IMG) { \
        const float* ipr = ip + r_ * IMG; \
        const float* tpr = tp + r_ * IMG; \
        xa = ipr[tid];       ya = tpr[tid]; \
        xb = ipr[tid + 256]; yb = tpr[tid + 256]; \
      } }

#define SS_HPH(KK, RP) \
    { const int oy_ = r0 + (KK) - 11; \
      if (oy_ < OUT_N) { \
        float A0=0.f,A1=0.f,A2=0.f,A3=0.f,B0=0.f,B1=0.f,B2=0.f,B3=0.f; \
        _Pragma("unroll") \
        for (int j = 0; j < 12; ++j) { \
          float4 v = buf[RP][tid + (j>>1) + (j&1)*EV_OFF]; \
          if (j <= 10) { float wj=g[j];   A0+=wj*v.x; A1+=wj*v.y; A2+=wj*v.z; A3+=wj*v.w; } \
          if (j >= 1)  { float wj=g[j-1]; B0+=wj*v.x; B1+=wj*v.y; B2+=wj*v.z; B3+=wj*v.w; } \
        } \
        const int c0_ = 2*tid; \
        if (c0_ < OUT_N)     acc += ssim_px(A0,A1,A2,A3); \
        if (c0_ + 1 < OUT_N) acc += ssim_px(B0,B1,B2,B3); \
      } }

#define SS_RING(SLOT) \
    { float sa_=xa+ya, da_=xa-ya; rA[SLOT] = make_float4(xa, ya, sa_*sa_, da_*da_); \
      float sb_=xb+yb, db_=xb-yb; rB[SLOT] = make_float4(xb, yb, sb_*sb_, db_*db_); }

#define SS_VWR(SLOT, WP) \
    { float4 va_ = make_float4(0.f,0.f,0.f,0.f); \
      float4 vb_ = make_float4(0.f,0.f,0.f,0.f); \
      _Pragma("unroll") \
      for (int i = 0; i < 11; ++i) { \
        const int sl_ = ((SLOT) + 2 + i) % 12;   /* input rows KK-10 .. KK */ \
        float wj = g[i]; \
        va_.x += wj*rA[sl_].x; va_.y += wj*rA[sl_].y; va_.z += wj*rA[sl_].z; va_.w += wj*rA[sl_].w; \
        vb_.x += wj*rB[sl_].x; vb_.y += wj*rB[sl_].y; vb_.z += wj*rB[sl_].z; vb_.w += wj*rB[sl_].w; \
      } \
      buf[WP][wrA] = va_; buf[WP][wrB] = vb_; }

#define SS_ITER(KK, SLOT, HEN, VEN) \
    { SS_LOAD(KK); \
      if (HEN) SS_HPH(KK, (((KK)&1)^1)); \
      SS_RING(SLOT); \
      if (VEN) SS_VWR(SLOT, ((KK)&1)); \
      if ((HEN) || (VEN)) __syncthreads(); }

    // k = 0..9: load + ring fill only (no LDS, no barrier)
    SS_ITER(0,0,0,0)  SS_ITER(1,1,0,0)  SS_ITER(2,2,0,0)  SS_ITER(3,3,0,0)
    SS_ITER(4,4,0,0)  SS_ITER(5,5,0,0)  SS_ITER(6,6,0,0)  SS_ITER(7,7,0,0)
    SS_ITER(8,8,0,0)  SS_ITER(9,9,0,0)
    // k = 10: first V write; k = 11..25: V + H (outputs r0 .. r0+14)
    SS_ITER(10,10,0,1)
    SS_ITER(11,11,1,1)
    SS_ITER(12,0,1,1)  SS_ITER(13,1,1,1)  SS_ITER(14,2,1,1)  SS_ITER(15,3,1,1)
    SS_ITER(16,4,1,1)  SS_ITER(17,5,1,1)  SS_ITER(18,6,1,1)  SS_ITER(19,7,1,1)
    SS_ITER(20,8,1,1)  SS_ITER(21,9,1,1)  SS_ITER(22,10,1,1) SS_ITER(23,11,1,1)
    SS_ITER(24,0,1,1)  SS_ITER(25,1,1,1)
    // tail: H for output row r0+15 (V row written at k=25 -> buf[1])
    SS_HPH(26, 1)

    // block reduction
    #pragma unroll
    for (int off = 32; off > 0; off >>= 1)
        acc += __shfl_down(acc, off, 64);
    const int lane = tid & 63, wv = tid >> 6;
    if (lane == 0) red[wv] = acc;
    __syncthreads();
    if (tid == 0)
        partial[plane * STRIPS + strip] = red[0] + red[1] + red[2] + red[3];
}

// Deterministic final reduction: fixed traversal, double accumulation.
__global__ __launch_bounds__(256) void ssim_final(
    const float* __restrict__ partial, int n, float* __restrict__ out)
{
    __shared__ double red[256];
    double s = 0.0;
    for (int i = threadIdx.x; i < n; i += 256) s += (double)partial[i];
    red[threadIdx.x] = s;
    __syncthreads();
    for (int off = 128; off > 0; off >>= 1) {
        if (threadIdx.x < off) red[threadIdx.x] += red[threadIdx.x + off];
        __syncthreads();
    }
    if (threadIdx.x == 0) out[0] = (float)(1.0 - red[0] / (double)NPLANE);
}

extern "C" void kernel_launch(void* const* d_in, const int* in_sizes, int n_in,
                              void* d_out, int out_size, void* d_ws, size_t ws_size,
                              hipStream_t stream) {
    const float* in  = (const float*)d_in[0];
    const float* tgt = (const float*)d_in[1];
    const float* wt  = (const float*)d_in[2];
    float* out  = (float*)d_out;
    float* part = (float*)d_ws;

    dim3 grid(STRIPS, NPLANE);   // 32 row-strips x 48 planes = 1536 blocks
    ssim_strip<<<grid, 256, 0, stream>>>(in, tgt, wt, part);
    ssim_final<<<1, 256, 0, stream>>>(part, STRIPS * NPLANE, out);
}